// Round 5
// baseline (487.444 us; speedup 1.0000x reference)
//
#include <hip/hip_runtime.h>

#define C_CH 256  // channels, fixed by the problem

// ---------------- Phase 1: NCHW -> NHWC transpose ----------------
__global__ __launch_bounds__(256) void nchw_to_nhwc(
    const float* __restrict__ in, float* __restrict__ out, int HW)
{
    __shared__ float lds[64 * 64];
    int ct = blockIdx.y & 3;          // c tile (C_CH/64 = 4)
    int b  = blockIdx.y >> 2;
    int hw0 = blockIdx.x << 6;
    int c0  = ct << 6;
    const float* ip = in  + (size_t)b * C_CH * HW;
    float*       op = out + (size_t)b * HW * C_CH;

    int t   = threadIdx.x;
    int q   = t & 15;
    int r0  = t >> 4;

#pragma unroll
    for (int k = 0; k < 4; ++k) {
        int c_local = r0 + (k << 4);
        const float4 v = *reinterpret_cast<const float4*>(
            ip + (size_t)(c0 + c_local) * HW + hw0 + (q << 2));
#pragma unroll
        for (int i = 0; i < 4; ++i) {
            int hw_local = (q << 2) + i;
            lds[(hw_local << 6) + ((c_local + hw_local) & 63)] = ((const float*)&v)[i];
        }
    }
    __syncthreads();
#pragma unroll
    for (int k = 0; k < 4; ++k) {
        int hw_local = r0 + (k << 4);
        float4 v;
#pragma unroll
        for (int j = 0; j < 4; ++j) {
            int c_local = (q << 2) + j;
            ((float*)&v)[j] = lds[(hw_local << 6) + ((c_local + hw_local) & 63)];
        }
        *reinterpret_cast<float4*>(
            op + (size_t)(hw0 + hw_local) * C_CH + c0 + (q << 2)) = v;
    }
}

// ---- separable 1-D weight window: 4 taps over [i0, i0+3] -------------------
// Samples at a = p+0.25, b = p+0.75 (times bin, plus lo). Returns i0 and the
// 4 merged tap weights (validity folded in, zero taps -> load skipped).
__device__ __forceinline__ void taps4(
    int p, float lo, float bin, int L, float* __restrict__ Wt, int& i0)
{
    const float Lf = (float)L, Lm1 = (float)(L - 1);
    float sa = fmaf((float)p + 0.25f, bin, lo);
    float sb = fmaf((float)p + 0.75f, bin, lo);
    float va = (sa > -1.0f && sa < Lf) ? 1.0f : 0.0f;
    float vb = (sb > -1.0f && sb < Lf) ? 1.0f : 0.0f;
    float ca = fminf(fmaxf(sa, 0.0f), Lm1);
    float cb = fminf(fmaxf(sb, 0.0f), Lm1);
    float fa = floorf(ca), fb_ = floorf(cb);
    int ia0 = (int)fa, ib0 = (int)fb_;
    float la = ca - fa, ha = 1.0f - la;
    float lb = cb - fb_, hb = 1.0f - lb;
    int ia1 = min(ia0 + 1, L - 1);
    int ib1 = min(ib0 + 1, L - 1);
    i0 = ia0;
    int ka1 = ia1 - ia0;          // 0 or 1
    int kb0 = ib0 - ia0;          // 0..2  (sample spacing bin/2 <= 1.43)
    int kb1 = ib1 - ia0;          // 0..3
    float wa0 = ha * va, wa1 = la * va;
    float wb0 = hb * vb, wb1 = lb * vb;
    Wt[0] = wa0 + (ka1 == 0 ? wa1 : 0.f) + (kb0 == 0 ? wb0 : 0.f) + (kb1 == 0 ? wb1 : 0.f);
    Wt[1] =       (ka1 == 1 ? wa1 : 0.f) + (kb0 == 1 ? wb0 : 0.f) + (kb1 == 1 ? wb1 : 0.f);
    Wt[2] =                                (kb0 == 2 ? wb0 : 0.f) + (kb1 == 2 ? wb1 : 0.f);
    Wt[3] =                                                         (kb1 == 3 ? wb1 : 0.f);
}

// ---------------- Phase 2: gather from NHWC with separable dedup -----------
// Block = 4 waves; wave = one sample position (256 ch as float4/lane).
// Loads = nonzero cells of the 4x4 row x col tap window (typ. 3x3 = 9,
// small ROIs 2x2 = 4, worst 16). Branches are wave-uniform (pos is uniform).
template<int P, int POS>
__global__ __launch_bounds__(256, 3) void roi_gather_nhwc(
    const float* __restrict__ nhwc, const float* __restrict__ rois,
    float* __restrict__ out, int H, int W, float scale, int N)
{
    constexpr int PITCH = 260;          // floats; 1040B rows, 16B aligned
    constexpr int NB = (P * P) / POS;   // row-blocks per ROI
    __shared__ float lds[POS * PITCH];

    const int G = N * NB;
    int bid = blockIdx.x;
    int virt = (G % 8 == 0) ? ((bid & 7) * (G >> 3) + (bid >> 3)) : bid;
    int n  = virt / NB;
    int rb = virt - n * NB;
    int ph0 = rb * (POS / P);

    const int lane = threadIdx.x & 63;
    const int wid  = threadIdx.x >> 6;
    const int c4   = lane << 2;

    const float* r = rois + n * 5;
    const int b = (int)r[0];
    const float x1 = fmaf(r[1], scale, -0.5f);
    const float y1 = fmaf(r[2], scale, -0.5f);
    const float x2 = fmaf(r[3], scale, -0.5f);
    const float y2 = fmaf(r[4], scale, -0.5f);
    const float bin_h = (y2 - y1) * (1.0f / P);
    const float bin_w = (x2 - x1) * (1.0f / P);
    const float* fb = nhwc + (size_t)b * H * W * C_CH;

    for (int pos = wid; pos < POS; pos += 4) {
        int ph = ph0 + pos / P;
        int pw = pos % P;

        float WY[4], WX[4];
        int r0, c0;
        taps4(ph, y1, bin_h, H, WY, r0);
        taps4(pw, x1, bin_w, W, WX, c0);
        WX[0] *= 0.25f; WX[1] *= 0.25f; WX[2] *= 0.25f; WX[3] *= 0.25f;  // mean /4

        float4 acc = {0.f, 0.f, 0.f, 0.f};
        const unsigned base = (unsigned)(r0 * W + c0);
#pragma unroll
        for (int k = 0; k < 4; ++k) {
            if (WY[k] != 0.0f) {               // wave-uniform branch
                const unsigned rowb = base + (unsigned)(k * W);
#pragma unroll
                for (int j = 0; j < 4; ++j) {
                    if (WX[j] != 0.0f) {       // wave-uniform branch
                        const float4 v = *reinterpret_cast<const float4*>(
                            fb + ((size_t)((rowb + j) << 8) + c4));
                        const float wt = WY[k] * WX[j];
                        acc.x = fmaf(wt, v.x, acc.x);
                        acc.y = fmaf(wt, v.y, acc.y);
                        acc.z = fmaf(wt, v.z, acc.z);
                        acc.w = fmaf(wt, v.w, acc.w);
                    }
                }
            }
        }
        *reinterpret_cast<float4*>(&lds[pos * PITCH + c4]) = acc;
    }
    __syncthreads();

    // write-out: out[n][c][ph0..][..]; pos fastest across lanes (round-3 layout)
    const size_t obase = (size_t)n * C_CH * (P * P) + (size_t)ph0 * P;
    for (int i = threadIdx.x; i < C_CH * POS; i += 256) {
        int c   = i / POS;
        int pos = i - c * POS;
        out[obase + (size_t)c * (P * P) + pos] = lds[pos * PITCH + c];
    }
}

// ---------------- Fallback: direct NCHW kernel (verified round 2) ----------
template<int P, int CPT>
__global__ __launch_bounds__(256) void roi_align_direct(
    const float* __restrict__ feat, const float* __restrict__ rois,
    float* __restrict__ out, int N, int H, int W, float scale)
{
    constexpr int CG = C_CH / CPT;
    int tid = blockIdx.x * blockDim.x + threadIdx.x;
    int total = N * CG * P * P;
    if (tid >= total) return;

    int pw = tid % P;
    int t  = tid / P;
    int ph = t % P;
    t /= P;
    int cg = t % CG;
    int n  = t / CG;

    const float* r = rois + n * 5;
    int b = (int)r[0];
    float x1 = fmaf(r[1], scale, -0.5f);
    float y1 = fmaf(r[2], scale, -0.5f);
    float x2 = fmaf(r[3], scale, -0.5f);
    float y2 = fmaf(r[4], scale, -0.5f);
    float bin_h = (y2 - y1) * (1.0f / P);
    float bin_w = (x2 - x1) * (1.0f / P);

    float acc[CPT];
#pragma unroll
    for (int j = 0; j < CPT; ++j) acc[j] = 0.0f;

    const int HW = H * W;
    const float* fp = feat + ((size_t)b * C_CH + (size_t)cg * CPT) * HW;

    float WY[4], WX[4];
    int r0, c0;
    taps4(ph, y1, bin_h, H, WY, r0);
    taps4(pw, x1, bin_w, W, WX, c0);
    WX[0] *= 0.25f; WX[1] *= 0.25f; WX[2] *= 0.25f; WX[3] *= 0.25f;

#pragma unroll
    for (int k = 0; k < 4; ++k) {
        if (WY[k] != 0.0f) {
            int rowb = (r0 + k) * W + c0;
#pragma unroll
            for (int m = 0; m < 4; ++m) {
                if (WX[m] != 0.0f) {
                    float wt = WY[k] * WX[m];
                    int sp = rowb + m;
#pragma unroll
                    for (int j = 0; j < CPT; ++j)
                        acc[j] = fmaf(wt, fp[(size_t)j * HW + sp], acc[j]);
                }
            }
        }
    }

    float* op = out + (((size_t)n * C_CH + (size_t)cg * CPT) * P + ph) * P + pw;
#pragma unroll
    for (int j = 0; j < CPT; ++j) op[(size_t)j * P * P] = acc[j];
}

// ---------------- host ----------------
extern "C" void kernel_launch(void* const* d_in, const int* in_sizes, int n_in,
                              void* d_out, int out_size, void* d_ws, size_t ws_size,
                              hipStream_t stream) {
    const float* feat1 = (const float*)d_in[0];  // (2,256,256,256)
    const float* feat2 = (const float*)d_in[1];  // (2,256,128,128)
    const float* feat3 = (const float*)d_in[2];  // (2,256,64,64)
    const float* rois  = (const float*)d_in[3];  // (N,5)
    const int N = in_sizes[3] / 5;

    float* out1 = (float*)d_out;
    float* out2 = out1 + (size_t)N * C_CH * 28 * 28;
    float* out3 = out2 + (size_t)N * C_CH * 14 * 14;

    const size_t e1 = (size_t)2 * C_CH * 256 * 256;
    const size_t e2 = (size_t)2 * C_CH * 128 * 128;
    const size_t e3 = (size_t)2 * C_CH * 64 * 64;

    size_t off = 0;
    float* t1 = nullptr; float* t2 = nullptr; float* t3 = nullptr;
    if (off + e1 * 4 <= ws_size) { t1 = (float*)((char*)d_ws + off); off += e1 * 4; }
    if (off + e2 * 4 <= ws_size) { t2 = (float*)((char*)d_ws + off); off += e2 * 4; }
    if (off + e3 * 4 <= ws_size) { t3 = (float*)((char*)d_ws + off); off += e3 * 4; }

    if (t1) nchw_to_nhwc<<<dim3(65536 / 64, 8), 256, 0, stream>>>(feat1, t1, 65536);
    if (t2) nchw_to_nhwc<<<dim3(16384 / 64, 8), 256, 0, stream>>>(feat2, t2, 16384);
    if (t3) nchw_to_nhwc<<<dim3( 4096 / 64, 8), 256, 0, stream>>>(feat3, t3,  4096);

    if (t1) {
        roi_gather_nhwc<28, 28><<<N * 28, 256, 0, stream>>>(t1, rois, out1, 256, 256, 0.25f, N);
    } else {
        int total = N * (C_CH / 4) * 28 * 28;
        roi_align_direct<28, 4><<<(total + 255) / 256, 256, 0, stream>>>(feat1, rois, out1, N, 256, 256, 0.25f);
    }
    if (t2) {
        roi_gather_nhwc<14, 28><<<N * 7, 256, 0, stream>>>(t2, rois, out2, 128, 128, 0.125f, N);
    } else {
        int total = N * (C_CH / 4) * 14 * 14;
        roi_align_direct<14, 4><<<(total + 255) / 256, 256, 0, stream>>>(feat2, rois, out2, N, 128, 128, 0.125f);
    }
    if (t3) {
        roi_gather_nhwc<7, 49><<<N * 1, 256, 0, stream>>>(t3, rois, out3, 64, 64, 0.0625f, N);
    } else {
        int total = N * (C_CH / 4) * 7 * 7;
        roi_align_direct<7, 4><<<(total + 255) / 256, 256, 0, stream>>>(feat3, rois, out3, N, 64, 64, 0.0625f);
    }
}

// Round 7
// 359.633 us; speedup vs baseline: 1.3554x; 1.3554x over previous
//
#include <hip/hip_runtime.h>

#define C_CH 256  // channels, fixed by the problem

__device__ __forceinline__ unsigned short f2bf_rne(float f) {
    unsigned u = __float_as_uint(f);
    u += 0x7FFFu + ((u >> 16) & 1u);   // round-to-nearest-even
    return (unsigned short)(u >> 16);
}

// ---------------- Phase 1: NCHW f32 -> NHWC bf16 transpose ----------------
// 64(hw) x 64(c) tile; float4 global loads, rotate-swizzled f32 LDS,
// ushort4 (8B) bf16 stores along c.
__global__ __launch_bounds__(256) void nchw_to_nhwc_bf16(
    const float* __restrict__ in, unsigned short* __restrict__ out, int HW)
{
    __shared__ float lds[64 * 64];
    int ct = blockIdx.y & 3;          // c tile (C_CH/64 = 4)
    int b  = blockIdx.y >> 2;
    int hw0 = blockIdx.x << 6;
    int c0  = ct << 6;
    const float* ip = in  + (size_t)b * C_CH * HW;
    unsigned short* op = out + (size_t)b * HW * C_CH;

    int t  = threadIdx.x;
    int q  = t & 15;
    int r0 = t >> 4;

#pragma unroll
    for (int k = 0; k < 4; ++k) {
        int c_local = r0 + (k << 4);
        const float4 v = *reinterpret_cast<const float4*>(
            ip + (size_t)(c0 + c_local) * HW + hw0 + (q << 2));
#pragma unroll
        for (int i = 0; i < 4; ++i) {
            int hw_local = (q << 2) + i;
            lds[(hw_local << 6) + ((c_local + hw_local) & 63)] = ((const float*)&v)[i];
        }
    }
    __syncthreads();
#pragma unroll
    for (int k = 0; k < 4; ++k) {
        int hw_local = r0 + (k << 4);
        ushort4 o;
#pragma unroll
        for (int j = 0; j < 4; ++j) {
            int c_local = (q << 2) + j;
            ((unsigned short*)&o)[j] =
                f2bf_rne(lds[(hw_local << 6) + ((c_local + hw_local) & 63)]);
        }
        *reinterpret_cast<ushort4*>(
            op + (size_t)(hw0 + hw_local) * C_CH + c0 + (q << 2)) = o;
    }
}

// ---------------- weight/offset computation for one sample position ----------
__device__ __forceinline__ void woff16(
    int ph, int pw, float y1, float x1, float bin_h, float bin_w,
    int H, int W, int c4, float* __restrict__ w, int* __restrict__ off)
{
    const float Hm1 = (float)(H - 1), Wm1 = (float)(W - 1);
    const float Hf = (float)H, Wf = (float)W;
#pragma unroll
    for (int iy = 0; iy < 2; ++iy) {
        float gy = (float)ph + (iy ? 0.75f : 0.25f);
        float yy = fmaf(gy, bin_h, y1);
        bool vy = (yy > -1.0f) && (yy < Hf);
        float yc = fminf(fmaxf(yy, 0.0f), Hm1);
        float y0f = floorf(yc);
        int   y0  = (int)y0f;
        float ly  = yc - y0f, hy = 1.0f - ly;
        int   y1i = min(y0 + 1, H - 1);
        int ro0 = y0 * W, ro1 = y1i * W;
#pragma unroll
        for (int ix = 0; ix < 2; ++ix) {
            float gx = (float)pw + (ix ? 0.75f : 0.25f);
            float xx = fmaf(gx, bin_w, x1);
            bool v = vy && (xx > -1.0f) && (xx < Wf);
            float xc = fminf(fmaxf(xx, 0.0f), Wm1);
            float x0f = floorf(xc);
            int   x0  = (int)x0f;
            float lx  = xc - x0f, hx = 1.0f - lx;
            int   x1i = min(x0 + 1, W - 1);
            float q = v ? 0.25f : 0.0f;
            int s = ((iy << 1) + ix) << 2;
            w[s + 0] = hy * hx * q;  off[s + 0] = ((ro0 + x0 ) << 8) + c4;
            w[s + 1] = hy * lx * q;  off[s + 1] = ((ro0 + x1i) << 8) + c4;
            w[s + 2] = ly * hx * q;  off[s + 2] = ((ro1 + x0 ) << 8) + c4;
            w[s + 3] = ly * lx * q;  off[s + 3] = ((ro1 + x1i) << 8) + c4;
        }
    }
}

// ---------------- Phase 2: gather from bf16 NHWC ----------------
// Block = 4 waves; wave = one sample position (256 ch; lane = 4 ch via 8B load).
// 16 unconditional corner loads (uint2, 512B/wave, coalesced), bf16->f32 via
// shift/and, f32 FMA accumulate. XCD-chunked block swizzle for L2 locality.
template<int P, int POS>
__global__ __launch_bounds__(256, 4) void roi_gather_nhwc(
    const unsigned short* __restrict__ nhwc, const float* __restrict__ rois,
    float* __restrict__ out, int H, int W, float scale, int N)
{
    constexpr int PITCH = 260;          // f32 per position row (1040B, 16B aligned)
    constexpr int NB = (P * P) / POS;   // row-blocks per ROI
    __shared__ float lds[POS * PITCH];

    const int G = N * NB;
    int bid = blockIdx.x;
    int virt = (G % 8 == 0) ? ((bid & 7) * (G >> 3) + (bid >> 3)) : bid;
    int n  = virt / NB;
    int rb = virt - n * NB;
    int ph0 = rb * (POS / P);

    const int lane = threadIdx.x & 63;
    const int wid  = threadIdx.x >> 6;
    const int c4   = lane << 2;

    const float* r = rois + n * 5;
    const int b = (int)r[0];
    const float x1 = fmaf(r[1], scale, -0.5f);
    const float y1 = fmaf(r[2], scale, -0.5f);
    const float x2 = fmaf(r[3], scale, -0.5f);
    const float y2 = fmaf(r[4], scale, -0.5f);
    const float bin_h = (y2 - y1) * (1.0f / P);
    const float bin_w = (x2 - x1) * (1.0f / P);
    const unsigned short* fb = nhwc + (size_t)b * H * W * C_CH;

    for (int pos = wid; pos < POS; pos += 4) {
        int ph = ph0 + pos / P;
        int pw = pos % P;

        float w[16];
        int   off[16];
        woff16(ph, pw, y1, x1, bin_h, bin_w, H, W, c4, w, off);

        uint2 v[16];
#pragma unroll
        for (int m = 0; m < 16; ++m)
            v[m] = *reinterpret_cast<const uint2*>(fb + (size_t)(unsigned)off[m]);

        float4 acc = {0.f, 0.f, 0.f, 0.f};
#pragma unroll
        for (int m = 0; m < 16; ++m) {
            float f0 = __uint_as_float(v[m].x << 16);
            float f1 = __uint_as_float(v[m].x & 0xFFFF0000u);
            float f2 = __uint_as_float(v[m].y << 16);
            float f3 = __uint_as_float(v[m].y & 0xFFFF0000u);
            acc.x = fmaf(w[m], f0, acc.x);
            acc.y = fmaf(w[m], f1, acc.y);
            acc.z = fmaf(w[m], f2, acc.z);
            acc.w = fmaf(w[m], f3, acc.w);
        }
        *reinterpret_cast<float4*>(&lds[pos * PITCH + c4]) = acc;
    }
    __syncthreads();

    // write-out: out[n][c][ph0..][..]
    const size_t obase = (size_t)n * C_CH * (P * P) + (size_t)ph0 * P;
    for (int i = threadIdx.x; i < C_CH * POS; i += 256) {
        int c   = i / POS;
        int pos = i - c * POS;
        out[obase + (size_t)c * (P * P) + pos] = lds[pos * PITCH + c];
    }
}

// ---------------- Fallback: direct NCHW kernel (verified round 2) ----------
template<int P, int CPT>
__global__ __launch_bounds__(256) void roi_align_direct(
    const float* __restrict__ feat, const float* __restrict__ rois,
    float* __restrict__ out, int N, int H, int W, float scale)
{
    constexpr int CG = C_CH / CPT;
    int tid = blockIdx.x * blockDim.x + threadIdx.x;
    int total = N * CG * P * P;
    if (tid >= total) return;

    int pw = tid % P;
    int t  = tid / P;
    int ph = t % P;
    t /= P;
    int cg = t % CG;
    int n  = t / CG;

    const float* r = rois + n * 5;
    int b = (int)r[0];
    float x1 = fmaf(r[1], scale, -0.5f);
    float y1 = fmaf(r[2], scale, -0.5f);
    float x2 = fmaf(r[3], scale, -0.5f);
    float y2 = fmaf(r[4], scale, -0.5f);
    float bin_h = (y2 - y1) * (1.0f / P);
    float bin_w = (x2 - x1) * (1.0f / P);

    float acc[CPT];
#pragma unroll
    for (int j = 0; j < CPT; ++j) acc[j] = 0.0f;

    const int HW = H * W;
    const float* fp = feat + ((size_t)b * C_CH + (size_t)cg * CPT) * HW;

    float w[16]; int off[16];
    woff16(ph, pw, y1, x1, bin_h, bin_w, H, W, 0, w, off);
#pragma unroll
    for (int m = 0; m < 16; ++m) {
        int sp = off[m] >> 8;
#pragma unroll
        for (int j = 0; j < CPT; ++j)
            acc[j] = fmaf(w[m], fp[(size_t)j * HW + sp], acc[j]);
    }

    float* op = out + (((size_t)n * C_CH + (size_t)cg * CPT) * P + ph) * P + pw;
#pragma unroll
    for (int j = 0; j < CPT; ++j) op[(size_t)j * P * P] = acc[j];
}

// ---------------- host ----------------
extern "C" void kernel_launch(void* const* d_in, const int* in_sizes, int n_in,
                              void* d_out, int out_size, void* d_ws, size_t ws_size,
                              hipStream_t stream) {
    const float* feat1 = (const float*)d_in[0];  // (2,256,256,256)
    const float* feat2 = (const float*)d_in[1];  // (2,256,128,128)
    const float* feat3 = (const float*)d_in[2];  // (2,256,64,64)
    const float* rois  = (const float*)d_in[3];  // (N,5)
    const int N = in_sizes[3] / 5;

    float* out1 = (float*)d_out;
    float* out2 = out1 + (size_t)N * C_CH * 28 * 28;
    float* out3 = out2 + (size_t)N * C_CH * 14 * 14;

    const size_t e1 = (size_t)2 * C_CH * 256 * 256;   // elements per level
    const size_t e2 = (size_t)2 * C_CH * 128 * 128;
    const size_t e3 = (size_t)2 * C_CH * 64 * 64;

    // bf16 workspace: 2 bytes per element, 16B-aligned chunks
    size_t off = 0;
    unsigned short* t1 = nullptr; unsigned short* t2 = nullptr; unsigned short* t3 = nullptr;
    if (off + e1 * 2 <= ws_size) { t1 = (unsigned short*)((char*)d_ws + off); off += e1 * 2; }
    if (off + e2 * 2 <= ws_size) { t2 = (unsigned short*)((char*)d_ws + off); off += e2 * 2; }
    if (off + e3 * 2 <= ws_size) { t3 = (unsigned short*)((char*)d_ws + off); off += e3 * 2; }

    if (t1) nchw_to_nhwc_bf16<<<dim3(65536 / 64, 8), 256, 0, stream>>>(feat1, t1, 65536);
    if (t2) nchw_to_nhwc_bf16<<<dim3(16384 / 64, 8), 256, 0, stream>>>(feat2, t2, 16384);
    if (t3) nchw_to_nhwc_bf16<<<dim3( 4096 / 64, 8), 256, 0, stream>>>(feat3, t3,  4096);

    if (t1) {
        roi_gather_nhwc<28, 28><<<N * 28, 256, 0, stream>>>(t1, rois, out1, 256, 256, 0.25f, N);
    } else {
        int total = N * (C_CH / 4) * 28 * 28;
        roi_align_direct<28, 4><<<(total + 255) / 256, 256, 0, stream>>>(feat1, rois, out1, N, 256, 256, 0.25f);
    }
    if (t2) {
        roi_gather_nhwc<14, 28><<<N * 7, 256, 0, stream>>>(t2, rois, out2, 128, 128, 0.125f, N);
    } else {
        int total = N * (C_CH / 4) * 14 * 14;
        roi_align_direct<14, 4><<<(total + 255) / 256, 256, 0, stream>>>(feat2, rois, out2, N, 128, 128, 0.125f);
    }
    if (t3) {
        roi_gather_nhwc<7, 49><<<N * 1, 256, 0, stream>>>(t3, rois, out3, 64, 64, 0.0625f, N);
    } else {
        int total = N * (C_CH / 4) * 7 * 7;
        roi_align_direct<7, 4><<<(total + 255) / 256, 256, 0, stream>>>(feat3, rois, out3, N, 64, 64, 0.0625f);
    }
}